// Round 3
// baseline (275.547 us; speedup 1.0000x reference)
//
#include <hip/hip_runtime.h>

// z = x @ W.T - b (65536x512 @ (256x512)^T) -> row-wise projection onto
// {y: |1^T y|<=S, ||y||^2<=R2}; projection is affine per row (y=a*z+b0),
// fused via per-row (t,zz) reductions.
//
// R3: NO LDS / NO BARRIERS in the K-loop. Rationale: BN=256 => x rows have
// zero cross-block reuse (LDS staging of A saves nothing vs L1), and W(bf16)
// is 256KB = fully L2-resident. Each wave streams A-frags from global
// (fp32 -> bf16 in regs) and B-frags from L2, fully pipelineable; waves
// never block each other. Block = 64 rows x 256 cols, 4 waves (one per
// 64-col quarter), each wave 64x64 via 4x4 of 16x16x32 MFMA. Grid = 1024.

typedef __bf16 bf16x8 __attribute__((ext_vector_type(8)));
typedef float f32x4 __attribute__((ext_vector_type(4)));

#define THREADS 256
#define BM 64

__device__ __forceinline__ unsigned short f2bf(float f) {
    unsigned u = __builtin_bit_cast(unsigned, f);
    u += 0x7fffu + ((u >> 16) & 1u);     // RNE
    return (unsigned short)(u >> 16);
}

// one-time: W fp32 [256][512] -> bf16 row-major in workspace
__global__ void wconv_kernel(const float* __restrict__ W,
                             unsigned short* __restrict__ Wb) {
    int i = (blockIdx.x * 256 + threadIdx.x) * 4;
    float4 v = *(const float4*)(W + i);
    ushort4 h;
    h.x = f2bf(v.x); h.y = f2bf(v.y); h.z = f2bf(v.z); h.w = f2bf(v.w);
    *(ushort4*)(Wb + i) = h;
}

__device__ __forceinline__ bf16x8 cvt8(float4 a, float4 b) {
    bf16x8 r;
    r[0] = (__bf16)a.x; r[1] = (__bf16)a.y; r[2] = (__bf16)a.z; r[3] = (__bf16)a.w;
    r[4] = (__bf16)b.x; r[5] = (__bf16)b.y; r[6] = (__bf16)b.z; r[7] = (__bf16)b.w;
    return r;
}

__global__ __launch_bounds__(THREADS, 3)
void proj_gemm_kernel(const float* __restrict__ x,
                      const unsigned short* __restrict__ Wb,
                      const float* __restrict__ bias,
                      float* __restrict__ out) {
    __shared__ float P[BM * 8];       // 64 rows x {4 waves x (t,zz)} = 2 KB
    __shared__ float AB[BM * 2];      // 64 x (alpha,beta)

    const int tid  = threadIdx.x;
    const int lane = tid & 63;
    const int wn   = tid >> 6;        // wave = 64-col quarter
    const int ln   = lane & 15;
    const int quad = lane >> 4;
    const long m0  = (long)blockIdx.x * BM;

    // A frag source: lane ln = row-in-16, quad*8 = k-chunk (8 consecutive fp32)
    const float* xa[4];
    #pragma unroll
    for (int mi = 0; mi < 4; ++mi)
        xa[mi] = x + (m0 + mi * 16 + ln) * 512 + quad * 8;
    // B frag source: 8 consecutive bf16 (16B dwordx4), L2-resident
    const unsigned short* wb[4];
    #pragma unroll
    for (int ni = 0; ni < 4; ++ni)
        wb[ni] = Wb + (long)(wn * 64 + ni * 16 + ln) * 512 + quad * 8;

    f32x4 acc[4][4];
    #pragma unroll
    for (int mi = 0; mi < 4; ++mi)
        #pragma unroll
        for (int ni = 0; ni < 4; ++ni)
            acc[mi][ni] = (f32x4){0.f, 0.f, 0.f, 0.f};

    // 16 k-steps of 32; no barriers anywhere in this loop.
    #pragma unroll 2
    for (int k = 0; k < 16; ++k) {
        const int k0 = k * 32;
        // issue HBM (A) loads first — longest latency
        float4 a0[4], a1[4];
        #pragma unroll
        for (int mi = 0; mi < 4; ++mi) {
            a0[mi] = *(const float4*)(xa[mi] + k0);
            a1[mi] = *(const float4*)(xa[mi] + k0 + 4);
        }
        bf16x8 bf[4];
        #pragma unroll
        for (int ni = 0; ni < 4; ++ni)
            bf[ni] = *(const bf16x8*)(wb[ni] + k0);
        #pragma unroll
        for (int mi = 0; mi < 4; ++mi) {
            bf16x8 af = cvt8(a0[mi], a1[mi]);
            #pragma unroll
            for (int ni = 0; ni < 4; ++ni)
                acc[mi][ni] = __builtin_amdgcn_mfma_f32_16x16x32_bf16(
                    af, bf[ni], acc[mi][ni], 0, 0, 0);
        }
    }

    // bias before row reductions
    float bb[4];
    #pragma unroll
    for (int ni = 0; ni < 4; ++ni) bb[ni] = bias[wn * 64 + ni * 16 + ln];
    #pragma unroll
    for (int mi = 0; mi < 4; ++mi)
        #pragma unroll
        for (int ni = 0; ni < 4; ++ni)
            #pragma unroll
            for (int r = 0; r < 4; ++r)
                acc[mi][ni][r] -= bb[ni];

    // per-row partials over this wave's 64 cols.
    // C/D layout: col = ln (per ni quarter), row-in-16 = quad*4 + r.
    #pragma unroll
    for (int mi = 0; mi < 4; ++mi) {
        #pragma unroll
        for (int r = 0; r < 4; ++r) {
            float s1 = 0.f, s2 = 0.f;
            #pragma unroll
            for (int ni = 0; ni < 4; ++ni) {
                float v = acc[mi][ni][r];
                s1 += v; s2 += v * v;
            }
            #pragma unroll
            for (int off = 1; off < 16; off <<= 1) {
                s1 += __shfl_xor(s1, off, 64);
                s2 += __shfl_xor(s2, off, 64);
            }
            if (ln == 0) {
                int row = mi * 16 + quad * 4 + r;
                P[row * 8 + wn * 2 + 0] = s1;
                P[row * 8 + wn * 2 + 1] = s2;
            }
        }
    }
    __syncthreads();

    // one thread per row: KKT case analysis -> (alpha, beta)
    if (tid < BM) {
        int row = tid;
        float t  = P[row*8+0] + P[row*8+2] + P[row*8+4] + P[row*8+6];
        float zz = P[row*8+1] + P[row*8+3] + P[row*8+5] + P[row*8+7];
        const float S = 0.1f, R2 = 0.02f, nf = 256.f, inv_n = 1.f / 256.f;
        float tc    = fminf(fmaxf(t, -S), S);
        float beta1 = (tc - t) * inv_n;
        float ny1   = zz + 2.f * beta1 * t + nf * beta1 * beta1;
        float alpha, beta;
        if (ny1 <= R2) {
            alpha = 1.f; beta = beta1;
        } else {
            float znorm = sqrtf(fmaxf(zz, 1e-12f));
            float scale = fminf(1.f, 0.14142135623730951f / znorm);
            if (fabsf(t) * scale <= S) {
                alpha = scale; beta = 0.f;
            } else {
                float denom = fmaxf(nf * zz - t * t, 1e-12f);
                float c  = sqrtf(5.11f / denom);             // n*R2 - S^2
                float sp = (t > 0.f) ? S : ((t < 0.f) ? -S : 0.f);
                alpha = c; beta = (sp - c * t) * inv_n;
            }
        }
        AB[row*2+0] = alpha;
        AB[row*2+1] = beta;
    }
    __syncthreads();

    // apply y = alpha*z + beta, store
    #pragma unroll
    for (int mi = 0; mi < 4; ++mi) {
        #pragma unroll
        for (int r = 0; r < 4; ++r) {
            int row = mi * 16 + quad * 4 + r;
            float alpha = AB[row*2+0];
            float beta  = AB[row*2+1];
            float* orow = out + (m0 + row) * 256 + wn * 64 + ln;
            #pragma unroll
            for (int ni = 0; ni < 4; ++ni)
                orow[ni*16] = alpha * acc[mi][ni][r] + beta;
        }
    }
}

extern "C" void kernel_launch(void* const* d_in, const int* in_sizes, int n_in,
                              void* d_out, int out_size, void* d_ws, size_t ws_size,
                              hipStream_t stream) {
    const float* x = (const float*)d_in[0];   // [65536, 512]
    const float* W = (const float*)d_in[1];   // [256, 512]
    const float* b = (const float*)d_in[2];   // [256]
    float* out = (float*)d_out;               // [65536, 256]
    unsigned short* Wb = (unsigned short*)d_ws; // 256KB bf16 W

    const int Dout = in_sizes[2];             // 256
    const int Din  = in_sizes[1] / Dout;      // 512
    const int Btot = in_sizes[0] / Din;       // 65536

    wconv_kernel<<<(Dout * Din) / (256 * 4), 256, 0, stream>>>(W, Wb);
    proj_gemm_kernel<<<Btot / BM, THREADS, 0, stream>>>(x, Wb, b, out);
}

// Round 4
// 227.083 us; speedup vs baseline: 1.2134x; 1.2134x over previous
//
#include <hip/hip_runtime.h>

// z = x @ W.T - b (65536x512 @ (256x512)^T) -> row-wise projection onto
// {y: |1^T y|<=S, ||y||^2<=R2}; projection is affine per row (y=a*z+b0),
// fused via per-row (t,zz) reductions.
//
// R4: A staged as FP32 via async global_load_lds (16B/lane), DOUBLE-BUFFERED,
// one barrier per K-tile. fp32->bf16 conversion happens at LDS->reg read time
// (overlapped with MFMA). B read direct from L2 (bf16 Wb, 256KB resident) with
// one-step register prefetch. BM=64, 256 thr, LDS ~34KB -> 4 blocks/CU,
// grid=1024 fully resident; inter-block stagger hides the per-barrier drain.
// A LDS layout: row-major 64x64 fp32, 16B chunks XOR-swizzled by row so the
// frag reads hit all 8 bank groups (BW floor) instead of 4.

typedef __bf16 bf16x8 __attribute__((ext_vector_type(8)));
typedef float f32x4 __attribute__((ext_vector_type(4)));

#define THREADS 256
#define BM 64

__device__ __forceinline__ unsigned short f2bf(float f) {
    unsigned u = __builtin_bit_cast(unsigned, f);
    u += 0x7fffu + ((u >> 16) & 1u);     // RNE
    return (unsigned short)(u >> 16);
}

// one-time: W fp32 [256][512] -> bf16 row-major in workspace
__global__ void wconv_kernel(const float* __restrict__ W,
                             unsigned short* __restrict__ Wb) {
    int i = (blockIdx.x * 256 + threadIdx.x) * 4;
    float4 v = *(const float4*)(W + i);
    ushort4 h;
    h.x = f2bf(v.x); h.y = f2bf(v.y); h.z = f2bf(v.z); h.w = f2bf(v.w);
    *(ushort4*)(Wb + i) = h;
}

__device__ __forceinline__ bf16x8 cvt8(float4 a, float4 b) {
    bf16x8 r;
    r[0] = (__bf16)a.x; r[1] = (__bf16)a.y; r[2] = (__bf16)a.z; r[3] = (__bf16)a.w;
    r[4] = (__bf16)b.x; r[5] = (__bf16)b.y; r[6] = (__bf16)b.z; r[7] = (__bf16)b.w;
    return r;
}

__global__ __launch_bounds__(THREADS, 4)
void proj_gemm_kernel(const float* __restrict__ x,
                      const unsigned short* __restrict__ Wb,
                      const float* __restrict__ bias,
                      float* __restrict__ out) {
    __shared__ alignas(16) float Abuf[2][BM * 64];   // 2 x 16 KB fp32 A tiles
    __shared__ float P[BM * 8];                      // per-row {t,zz} x 4 waves
    __shared__ float AB[BM * 2];                     // per-row alpha/beta

    const int tid  = threadIdx.x;
    const int lane = tid & 63;
    const int wn   = tid >> 6;        // wave = 64-col quarter of N
    const int ln   = lane & 15;
    const int quad = lane >> 4;
    const long m0  = (long)blockIdx.x * BM;

    // B frag pointers (bf16, L2-resident): 16B per lane
    const unsigned short* wb[4];
    #pragma unroll
    for (int ni = 0; ni < 4; ++ni)
        wb[ni] = Wb + (long)(wn * 64 + ni * 16 + ln) * 512 + quad * 8;

    f32x4 acc[4][4];
    #pragma unroll
    for (int mi = 0; mi < 4; ++mi)
        #pragma unroll
        for (int ni = 0; ni < 4; ++ni)
            acc[mi][ni] = (f32x4){0.f, 0.f, 0.f, 0.f};

    // ---- A staging: tile kt covers k in [kt*64, kt*64+64), 16KB fp32.
    // 4 DMA instrs/thread; flat chunk ff = j*256+tid -> row=ff>>4, slot=ff&15,
    // source chunk c = slot ^ (row&15)  (XOR swizzle, read-side bank spread).
    auto stage = [&](int kt, int bufsel) {
        const int k0 = kt * 64;
        #pragma unroll
        for (int j = 0; j < 4; ++j) {
            const int ff  = j * 256 + tid;
            const int row = ff >> 4;
            const int sl  = ff & 15;
            const int c   = sl ^ (row & 15);
            const float* src = x + (m0 + row) * 512 + k0 + c * 4;
            __builtin_amdgcn_global_load_lds(
                (const __attribute__((address_space(1))) void*)src,
                (__attribute__((address_space(3))) void*)(unsigned long)(unsigned int)
                    (unsigned long)(uintptr_t)&Abuf[bufsel][ff * 4],
                16, 0, 0);
        }
    };

    stage(0, 0);

    // B prefetch for kk=0
    bf16x8 bcur[4];
    #pragma unroll
    for (int ni = 0; ni < 4; ++ni)
        bcur[ni] = *(const bf16x8*)(wb[ni]);

    for (int kt = 0; kt < 8; ++kt) {
        __syncthreads();              // drain: buf[kt&1] staged; old reads done
        if (kt < 7) stage(kt + 1, (kt + 1) & 1);
        const float* buf = Abuf[kt & 1];
        #pragma unroll
        for (int ks = 0; ks < 2; ++ks) {
            const int kk = kt * 2 + ks;
            // prefetch next B frags (L2) while computing current
            bf16x8 bnext[4];
            const int kkn = (kk < 15) ? kk + 1 : 15;
            #pragma unroll
            for (int ni = 0; ni < 4; ++ni)
                bnext[ni] = *(const bf16x8*)(wb[ni] + kkn * 32);
            #pragma unroll
            for (int mi = 0; mi < 4; ++mi) {
                const int row = mi * 16 + ln;
                const int c0  = ks * 8 + quad * 2;
                const float* rbase = buf + row * 64;
                float4 lo = *(const float4*)&rbase[((c0    ) ^ ln) * 4];
                float4 hi = *(const float4*)&rbase[((c0 + 1) ^ ln) * 4];
                bf16x8 af = cvt8(lo, hi);
                #pragma unroll
                for (int ni = 0; ni < 4; ++ni)
                    acc[mi][ni] = __builtin_amdgcn_mfma_f32_16x16x32_bf16(
                        af, bcur[ni], acc[mi][ni], 0, 0, 0);
            }
            #pragma unroll
            for (int ni = 0; ni < 4; ++ni) bcur[ni] = bnext[ni];
        }
    }

    // bias before row reductions
    float bb[4];
    #pragma unroll
    for (int ni = 0; ni < 4; ++ni) bb[ni] = bias[wn * 64 + ni * 16 + ln];
    #pragma unroll
    for (int mi = 0; mi < 4; ++mi)
        #pragma unroll
        for (int ni = 0; ni < 4; ++ni)
            #pragma unroll
            for (int r = 0; r < 4; ++r)
                acc[mi][ni][r] -= bb[ni];

    // per-row partials over this wave's 64 cols.
    // C/D layout: col = ln (per ni quarter), row-in-16 = quad*4 + r.
    #pragma unroll
    for (int mi = 0; mi < 4; ++mi) {
        #pragma unroll
        for (int r = 0; r < 4; ++r) {
            float s1 = 0.f, s2 = 0.f;
            #pragma unroll
            for (int ni = 0; ni < 4; ++ni) {
                float v = acc[mi][ni][r];
                s1 += v; s2 += v * v;
            }
            #pragma unroll
            for (int off = 1; off < 16; off <<= 1) {
                s1 += __shfl_xor(s1, off, 64);
                s2 += __shfl_xor(s2, off, 64);
            }
            if (ln == 0) {
                int row = mi * 16 + quad * 4 + r;
                P[row * 8 + wn * 2 + 0] = s1;
                P[row * 8 + wn * 2 + 1] = s2;
            }
        }
    }
    __syncthreads();

    // one thread per row: KKT case analysis -> (alpha, beta)
    if (tid < BM) {
        int row = tid;
        float t  = P[row*8+0] + P[row*8+2] + P[row*8+4] + P[row*8+6];
        float zz = P[row*8+1] + P[row*8+3] + P[row*8+5] + P[row*8+7];
        const float S = 0.1f, R2 = 0.02f, nf = 256.f, inv_n = 1.f / 256.f;
        float tc    = fminf(fmaxf(t, -S), S);
        float beta1 = (tc - t) * inv_n;
        float ny1   = zz + 2.f * beta1 * t + nf * beta1 * beta1;
        float alpha, beta;
        if (ny1 <= R2) {
            alpha = 1.f; beta = beta1;
        } else {
            float znorm = sqrtf(fmaxf(zz, 1e-12f));
            float scale = fminf(1.f, 0.14142135623730951f / znorm);
            if (fabsf(t) * scale <= S) {
                alpha = scale; beta = 0.f;
            } else {
                float denom = fmaxf(nf * zz - t * t, 1e-12f);
                float c  = sqrtf(5.11f / denom);             // n*R2 - S^2
                float sp = (t > 0.f) ? S : ((t < 0.f) ? -S : 0.f);
                alpha = c; beta = (sp - c * t) * inv_n;
            }
        }
        AB[row*2+0] = alpha;
        AB[row*2+1] = beta;
    }
    __syncthreads();

    // apply y = alpha*z + beta, store
    #pragma unroll
    for (int mi = 0; mi < 4; ++mi) {
        #pragma unroll
        for (int r = 0; r < 4; ++r) {
            int row = mi * 16 + quad * 4 + r;
            float alpha = AB[row*2+0];
            float beta  = AB[row*2+1];
            float* orow = out + (m0 + row) * 256 + wn * 64 + ln;
            #pragma unroll
            for (int ni = 0; ni < 4; ++ni)
                orow[ni*16] = alpha * acc[mi][ni][r] + beta;
        }
    }
}

extern "C" void kernel_launch(void* const* d_in, const int* in_sizes, int n_in,
                              void* d_out, int out_size, void* d_ws, size_t ws_size,
                              hipStream_t stream) {
    const float* x = (const float*)d_in[0];   // [65536, 512]
    const float* W = (const float*)d_in[1];   // [256, 512]
    const float* b = (const float*)d_in[2];   // [256]
    float* out = (float*)d_out;               // [65536, 256]
    unsigned short* Wb = (unsigned short*)d_ws; // 256KB bf16 W

    const int Dout = in_sizes[2];             // 256
    const int Din  = in_sizes[1] / Dout;      // 512
    const int Btot = in_sizes[0] / Din;       // 65536

    wconv_kernel<<<(Dout * Din) / (256 * 4), 256, 0, stream>>>(W, Wb);
    proj_gemm_kernel<<<Btot / BM, THREADS, 0, stream>>>(x, Wb, b, out);
}